// Round 4
// baseline (475.846 us; speedup 1.0000x reference)
//
#include <hip/hip_runtime.h>
#include <hip/hip_bf16.h>
#include <cstdint>
#include <cstddef>

#define B_  64
#define S_  2048
#define E_  512
#define C_  512
#define H_  256

using f32x4 = __attribute__((ext_vector_type(4))) float;
using s16x8 = __attribute__((ext_vector_type(8))) short;

// packed fp32x4 -> bf16x4 (RNE), via __float22bfloat162_rn (packed cvt on gfx950)
__device__ __forceinline__ uint2 f4_to_bf4(float4 v) {
    __hip_bfloat162 lo = __float22bfloat162_rn(make_float2(v.x, v.y));
    __hip_bfloat162 hi = __float22bfloat162_rn(make_float2(v.z, v.w));
    union { __hip_bfloat162 b; unsigned u; } a, c;
    a.b = lo; c.b = hi;
    return make_uint2(a.u, c.u);
}

// ---- prep: convert W_word to bf16 in ws ----
__global__ void prep_w(const float* __restrict__ W, unsigned short* __restrict__ Wb) {
    int i = (blockIdx.x * 256 + threadIdx.x) * 4;
    float4 v = *(const float4*)(W + i);
    uint2 o = f4_to_bf4(v);
    *(uint2*)(Wb + i) = o;
}

// ---- prep: cb[b][h] = ctx[b]@W_ctx[h]^T + b_ctx[h] + b_word[h] ----
__global__ void prep_ctx(const float* __restrict__ ctx, const float* __restrict__ Wc,
                         const float* __restrict__ bc, const float* __restrict__ bw,
                         float* __restrict__ cb) {
    __shared__ float row[C_];
    int b = blockIdx.x, t = threadIdx.x;
    row[t] = ctx[b * C_ + t];
    row[t + 256] = ctx[b * C_ + t + 256];
    __syncthreads();
    const float4* w4 = (const float4*)(Wc + (size_t)t * C_);
    const float4* x4 = (const float4*)row;
    float acc = 0.f;
    #pragma unroll 4
    for (int c = 0; c < C_ / 4; ++c) {
        float4 w = w4[c], x = x4[c];
        acc += w.x * x.x + w.y * x.y + w.z * x.z + w.w * x.w;
    }
    cb[b * H_ + t] = acc + bc[t] + bw[t];
}

// ---- main: scores[b,s] = w_hidden . tanh(embeds[b,s]@W_word^T + cb[b]) ----
#define BM 128
#define BN 256
#define BK 64
#define LDT 72   // padded LDS row stride (shorts)

__global__ __launch_bounds__(512) void scores_kernel(
    const float* __restrict__ A,            // [B*S, E] fp32
    const unsigned short* __restrict__ Wb,  // [H, E] bf16
    const float* __restrict__ cb,           // [B, H]
    const float* __restrict__ wh,           // [H]
    const int*   __restrict__ lens,         // [B]
    float* __restrict__ scores)             // [B*S]
{
    __shared__ __align__(16) unsigned short At[BM * LDT];
    __shared__ __align__(16) unsigned short Bt[BN * LDT];
    __shared__ float sblk[BM];
    int t = threadIdx.x;
    int m0 = blockIdx.x * BM;
    int b  = m0 >> 11;   // /S_
    int ms = m0 & (S_ - 1);
    if (ms >= lens[b]) return;   // fully-masked slab: dead work

    int w = t >> 6, lane = t & 63, quad = lane >> 4, lm = lane & 15;
    int wm = (w & 1) * 64, wn = (w >> 1) * 64;

    if (t < BM) sblk[t] = 0.f;

    f32x4 acc[4][4] = {};

    int arow = t >> 4, acol = (t & 15) * 4;  // A staging: 32 rows/sweep, 4 sweeps
    int brow = t >> 3, bcol = (t & 7) * 8;   // W staging: 64 rows/sweep, 4 sweeps

    const float* Ab = A + (size_t)m0 * E_;

    // register double-buffer: iter-0 staging loads issued up front
    float4 aR[4];
    uint4  bR[4];
    #pragma unroll
    for (int i = 0; i < 4; ++i)
        aR[i] = *(const float4*)(Ab + (size_t)(arow + i * 32) * E_ + acol);
    #pragma unroll
    for (int i = 0; i < 4; ++i)
        bR[i] = *(const uint4*)(Wb + (size_t)(brow + i * 64) * E_ + bcol);

    for (int k0 = 0; k0 < E_; k0 += BK) {
        #pragma unroll
        for (int i = 0; i < 4; ++i)
            *(uint2*)(At + (arow + i * 32) * LDT + acol) = f4_to_bf4(aR[i]);
        #pragma unroll
        for (int i = 0; i < 4; ++i)
            *(uint4*)(Bt + (brow + i * 64) * LDT + bcol) = bR[i];
        __syncthreads();
        // issue next iter's global loads NOW: HBM latency overlaps the MFMA loop
        int k1 = k0 + BK;
        if (k1 < E_) {
            #pragma unroll
            for (int i = 0; i < 4; ++i)
                aR[i] = *(const float4*)(Ab + (size_t)(arow + i * 32) * E_ + k1 + acol);
            #pragma unroll
            for (int i = 0; i < 4; ++i)
                bR[i] = *(const uint4*)(Wb + (size_t)(brow + i * 64) * E_ + k1 + bcol);
        }
        #pragma unroll
        for (int ks = 0; ks < 2; ++ks) {
            s16x8 af[4], bfr[4];
            #pragma unroll
            for (int i = 0; i < 4; ++i)
                af[i] = *(const s16x8*)(At + (wm + i * 16 + lm) * LDT + ks * 32 + quad * 8);
            #pragma unroll
            for (int i = 0; i < 4; ++i)
                bfr[i] = *(const s16x8*)(Bt + (wn + i * 16 + lm) * LDT + ks * 32 + quad * 8);
            #pragma unroll
            for (int mi = 0; mi < 4; ++mi)
                #pragma unroll
                for (int ni = 0; ni < 4; ++ni)
                    acc[mi][ni] = __builtin_amdgcn_mfma_f32_16x16x32_bf16(
                        af[mi], bfr[ni], acc[mi][ni], 0, 0, 0);
        }
        __syncthreads();
    }

    float wv[4], cbv[4];
    #pragma unroll
    for (int ni = 0; ni < 4; ++ni) {
        int n = wn + ni * 16 + lm;
        wv[ni]  = wh[n];
        cbv[ni] = cb[b * H_ + n];
    }
    #pragma unroll
    for (int mi = 0; mi < 4; ++mi) {
        #pragma unroll
        for (int r = 0; r < 4; ++r) {
            float p = 0.f;
            #pragma unroll
            for (int ni = 0; ni < 4; ++ni) {
                float x = acc[mi][ni][r] + cbv[ni];
                x = fminf(fmaxf(x, -15.f), 15.f);
                float e = __expf(2.f * x);
                float th = 1.f - 2.f * __builtin_amdgcn_rcpf(e + 1.f);
                p += wv[ni] * th;
            }
            #pragma unroll
            for (int off = 8; off >= 1; off >>= 1)
                p += __shfl_xor(p, off);
            if (lm == 0)
                atomicAdd(&sblk[wm + mi * 16 + quad * 4 + r], p);
        }
    }
    __syncthreads();
    if (t < BM) scores[m0 + t] = sblk[t];
}

// ---- masked softmax over s<len; attn=0 for s>=len. (1e-10*z term dropped:
// rel err <= ~4e-6, far under threshold; rows s>=len never read.)
__global__ void softmax_kernel(const int* __restrict__ lens, float* __restrict__ attn) {
    __shared__ float redm[4], redt[4];
    int b = blockIdx.x, t = threadIdx.x;
    int len = lens[b];
    float* sc = attn + (size_t)b * S_;
    float v[8];
    #pragma unroll
    for (int i = 0; i < 8; ++i) {
        int s = t + i * 256;
        v[i] = (s < len) ? sc[s] : -1e30f;
    }
    float m = -1e30f;
    #pragma unroll
    for (int i = 0; i < 8; ++i) m = fmaxf(m, v[i]);
    #pragma unroll
    for (int off = 32; off >= 1; off >>= 1) m = fmaxf(m, __shfl_xor(m, off));
    if ((t & 63) == 0) redm[t >> 6] = m;
    __syncthreads();
    m = fmaxf(fmaxf(redm[0], redm[1]), fmaxf(redm[2], redm[3]));
    float e[8]; float tm = 0.f;
    #pragma unroll
    for (int i = 0; i < 8; ++i) {
        int s = t + i * 256;
        e[i] = (s < len) ? __expf(v[i] - m) : 0.f;
        tm += e[i];
    }
    #pragma unroll
    for (int off = 32; off >= 1; off >>= 1) tm += __shfl_xor(tm, off);
    if ((t & 63) == 0) redt[t >> 6] = tm;
    __syncthreads();
    tm = redt[0] + redt[1] + redt[2] + redt[3];
    float sfac = 1.f / tm;
    #pragma unroll
    for (int i = 0; i < 8; ++i) {
        int s = t + i * 256;
        sc[s] = e[i] * sfac;
    }
}

// ---- attention_features[b,e] = sum_{s<len} attn[b,s]*embeds[b,s,e] ----
// float4 loads (1 KB/wave-inst), 4 rows in flight, LDS reduce, 4 atomics/thread<128.
__global__ __launch_bounds__(512) void wsum_kernel(
    const float* __restrict__ A, const float* __restrict__ attn,
    const int* __restrict__ lens, float* __restrict__ out) {
    int b = blockIdx.y;
    int len = lens[b];
    int s0 = blockIdx.x * 128;
    if (s0 >= len) return;
    int send = s0 + 128; if (send > len) send = len;
    int t  = threadIdx.x;
    int e4 = t & 127;   // float4 column
    int sr = t >> 7;    // row group 0..3
    const float* ap = attn + (size_t)b * S_;
    f32x4 acc = {0.f, 0.f, 0.f, 0.f};
    const float* base = A + (size_t)b * S_ * E_;
    for (int s = s0 + sr; s < send; s += 4) {
        float wgt = ap[s];
        f32x4 v = *(const f32x4*)(base + (size_t)s * E_ + e4 * 4);
        acc += wgt * v;
    }
    __shared__ f32x4 red[4][128];
    red[sr][e4] = acc;
    __syncthreads();
    if (t < 128) {
        f32x4 tot = red[0][t] + red[1][t] + red[2][t] + red[3][t];
        float* o = out + (size_t)b * E_ + t * 4;
        atomicAdd(o + 0, tot[0]);
        atomicAdd(o + 1, tot[1]);
        atomicAdd(o + 2, tot[2]);
        atomicAdd(o + 3, tot[3]);
    }
}

extern "C" void kernel_launch(void* const* d_in, const int* in_sizes, int n_in,
                              void* d_out, int out_size, void* d_ws, size_t ws_size,
                              hipStream_t stream) {
    const float* embeds = (const float*)d_in[0];
    const int*   lens   = (const int*)d_in[1];
    const float* ctx    = (const float*)d_in[2];
    const float* Ww     = (const float*)d_in[3];
    const float* bw     = (const float*)d_in[4];
    const float* Wc     = (const float*)d_in[5];
    const float* bc     = (const float*)d_in[6];
    const float* wh     = (const float*)d_in[7];
    float* out  = (float*)d_out;
    float* feat = out;                 // [B, E]
    float* attn = out + B_ * E_;       // [B, S] (raw scores, then attn; 0 for s>=len)

    unsigned short* Wb = (unsigned short*)d_ws;                                  // 256 KB
    float* cb = (float*)((char*)d_ws + (size_t)H_ * E_ * sizeof(unsigned short)); // 64 KB

    hipMemsetAsync(feat, 0, (size_t)B_ * E_ * sizeof(float), stream);
    prep_w<<<(H_ * E_) / 1024, 256, 0, stream>>>(Ww, Wb);
    prep_ctx<<<B_, 256, 0, stream>>>(ctx, Wc, bc, bw, cb);
    scores_kernel<<<dim3(B_ * S_ / BM), 512, 0, stream>>>(embeds, Wb, cb, wh, lens, attn);
    softmax_kernel<<<B_, 256, 0, stream>>>(lens, attn);
    wsum_kernel<<<dim3(S_ / 128, B_), 512, 0, stream>>>(embeds, attn, lens, feat);
}

// Round 5
// 428.731 us; speedup vs baseline: 1.1099x; 1.1099x over previous
//
#include <hip/hip_runtime.h>
#include <hip/hip_bf16.h>
#include <cstdint>
#include <cstddef>

#define B_  64
#define S_  2048
#define E_  512
#define C_  512
#define H_  256

using f32x4 = __attribute__((ext_vector_type(4))) float;
using s16x8 = __attribute__((ext_vector_type(8))) short;

// packed fp32x4 -> bf16x4 (RNE), via __float22bfloat162_rn (packed cvt on gfx950)
__device__ __forceinline__ uint2 f4_to_bf4(float4 v) {
    __hip_bfloat162 lo = __float22bfloat162_rn(make_float2(v.x, v.y));
    __hip_bfloat162 hi = __float22bfloat162_rn(make_float2(v.z, v.w));
    union { __hip_bfloat162 b; unsigned u; } a, c;
    a.b = lo; c.b = hi;
    return make_uint2(a.u, c.u);
}

// ---- prep: convert W_word to bf16 in ws ----
__global__ void prep_w(const float* __restrict__ W, unsigned short* __restrict__ Wb) {
    int i = (blockIdx.x * 256 + threadIdx.x) * 4;
    float4 v = *(const float4*)(W + i);
    uint2 o = f4_to_bf4(v);
    *(uint2*)(Wb + i) = o;
}

// ---- prep: cb[b][h] = ctx[b]@W_ctx[h]^T + b_ctx[h] + b_word[h] ----
__global__ void prep_ctx(const float* __restrict__ ctx, const float* __restrict__ Wc,
                         const float* __restrict__ bc, const float* __restrict__ bw,
                         float* __restrict__ cb) {
    __shared__ float row[C_];
    int b = blockIdx.x, t = threadIdx.x;
    row[t] = ctx[b * C_ + t];
    row[t + 256] = ctx[b * C_ + t + 256];
    __syncthreads();
    const float4* w4 = (const float4*)(Wc + (size_t)t * C_);
    const float4* x4 = (const float4*)row;
    float acc = 0.f;
    #pragma unroll 4
    for (int c = 0; c < C_ / 4; ++c) {
        float4 w = w4[c], x = x4[c];
        acc += w.x * x.x + w.y * x.y + w.z * x.z + w.w * x.w;
    }
    cb[b * H_ + t] = acc + bc[t] + bw[t];
}

// ---- main: scores[b,s] = w_hidden . tanh(embeds[b,s]@W_word^T + cb[b]) ----
// R2 structure: compiler-scheduled staging (NO register double-buffer — that
// pushed VGPR past the 128 cliff at 512 threads and halved blocks/CU in R3).
#define BM 128
#define BN 256
#define BK 64
#define LDT 72   // padded LDS row stride (shorts)

__global__ __launch_bounds__(512) void scores_kernel(
    const float* __restrict__ A,            // [B*S, E] fp32
    const unsigned short* __restrict__ Wb,  // [H, E] bf16
    const float* __restrict__ cb,           // [B, H]
    const float* __restrict__ wh,           // [H]
    const int*   __restrict__ lens,         // [B]
    float* __restrict__ scores)             // [B*S]
{
    __shared__ __align__(16) unsigned short At[BM * LDT];
    __shared__ __align__(16) unsigned short Bt[BN * LDT];
    __shared__ float sblk[BM];
    int t = threadIdx.x;
    int m0 = blockIdx.x * BM;
    int b  = m0 >> 11;   // /S_
    int ms = m0 & (S_ - 1);
    if (ms >= lens[b]) return;   // fully-masked slab: dead work

    int w = t >> 6, lane = t & 63, quad = lane >> 4, lm = lane & 15;
    int wm = (w & 1) * 64, wn = (w >> 1) * 64;

    if (t < BM) sblk[t] = 0.f;

    f32x4 acc[4][4] = {};

    int arow = t >> 4, acol = (t & 15) * 4;  // A staging: 32 rows/sweep, 4 sweeps
    int brow = t >> 3, bcol = (t & 7) * 8;   // W staging: 64 rows/sweep, 4 sweeps

    for (int k0 = 0; k0 < E_; k0 += BK) {
        #pragma unroll
        for (int i = 0; i < 4; ++i) {
            int r = arow + i * 32;
            float4 v = *(const float4*)(A + (size_t)(m0 + r) * E_ + k0 + acol);
            *(uint2*)(At + r * LDT + acol) = f4_to_bf4(v);
        }
        #pragma unroll
        for (int i = 0; i < 4; ++i) {
            int r = brow + i * 64;
            uint4 v = *(const uint4*)(Wb + (size_t)r * E_ + k0 + bcol);
            *(uint4*)(Bt + r * LDT + bcol) = v;
        }
        __syncthreads();
        #pragma unroll
        for (int ks = 0; ks < 2; ++ks) {
            s16x8 af[4], bfr[4];
            #pragma unroll
            for (int i = 0; i < 4; ++i)
                af[i] = *(const s16x8*)(At + (wm + i * 16 + lm) * LDT + ks * 32 + quad * 8);
            #pragma unroll
            for (int i = 0; i < 4; ++i)
                bfr[i] = *(const s16x8*)(Bt + (wn + i * 16 + lm) * LDT + ks * 32 + quad * 8);
            #pragma unroll
            for (int mi = 0; mi < 4; ++mi)
                #pragma unroll
                for (int ni = 0; ni < 4; ++ni)
                    acc[mi][ni] = __builtin_amdgcn_mfma_f32_16x16x32_bf16(
                        af[mi], bfr[ni], acc[mi][ni], 0, 0, 0);
        }
        __syncthreads();
    }

    float wv[4], cbv[4];
    #pragma unroll
    for (int ni = 0; ni < 4; ++ni) {
        int n = wn + ni * 16 + lm;
        wv[ni]  = wh[n];
        cbv[ni] = cb[b * H_ + n];
    }
    #pragma unroll
    for (int mi = 0; mi < 4; ++mi) {
        #pragma unroll
        for (int r = 0; r < 4; ++r) {
            float p = 0.f;
            #pragma unroll
            for (int ni = 0; ni < 4; ++ni) {
                float x = acc[mi][ni][r] + cbv[ni];
                x = fminf(fmaxf(x, -15.f), 15.f);
                float e = __expf(2.f * x);
                float th = 1.f - 2.f * __builtin_amdgcn_rcpf(e + 1.f);
                p += wv[ni] * th;
            }
            #pragma unroll
            for (int off = 8; off >= 1; off >>= 1)
                p += __shfl_xor(p, off);
            if (lm == 0)
                atomicAdd(&sblk[wm + mi * 16 + quad * 4 + r], p);
        }
    }
    __syncthreads();
    if (t < BM) scores[m0 + t] = sblk[t];
}

// ---- masked softmax over s<len; attn=0 for s>=len. (1e-10*z term dropped:
// rel err <= ~4e-6, far under threshold; rows s>=len never read.)
__global__ void softmax_kernel(const int* __restrict__ lens, float* __restrict__ attn) {
    __shared__ float redm[4], redt[4];
    int b = blockIdx.x, t = threadIdx.x;
    int len = lens[b];
    float* sc = attn + (size_t)b * S_;
    float v[8];
    #pragma unroll
    for (int i = 0; i < 8; ++i) {
        int s = t + i * 256;
        v[i] = (s < len) ? sc[s] : -1e30f;
    }
    float m = -1e30f;
    #pragma unroll
    for (int i = 0; i < 8; ++i) m = fmaxf(m, v[i]);
    #pragma unroll
    for (int off = 32; off >= 1; off >>= 1) m = fmaxf(m, __shfl_xor(m, off));
    if ((t & 63) == 0) redm[t >> 6] = m;
    __syncthreads();
    m = fmaxf(fmaxf(redm[0], redm[1]), fmaxf(redm[2], redm[3]));
    float e[8]; float tm = 0.f;
    #pragma unroll
    for (int i = 0; i < 8; ++i) {
        int s = t + i * 256;
        e[i] = (s < len) ? __expf(v[i] - m) : 0.f;
        tm += e[i];
    }
    #pragma unroll
    for (int off = 32; off >= 1; off >>= 1) tm += __shfl_xor(tm, off);
    if ((t & 63) == 0) redt[t >> 6] = tm;
    __syncthreads();
    tm = redt[0] + redt[1] + redt[2] + redt[3];
    float sfac = 1.f / tm;
    #pragma unroll
    for (int i = 0; i < 8; ++i) {
        int s = t + i * 256;
        sc[s] = e[i] * sfac;
    }
}

// ---- attention_features[b,e] = sum_{s<len} attn[b,s]*embeds[b,s,e] ----
// float4 loads (1 KB/wave-inst), 4 rows in flight, LDS reduce, 4 atomics/thread<128.
__global__ __launch_bounds__(512) void wsum_kernel(
    const float* __restrict__ A, const float* __restrict__ attn,
    const int* __restrict__ lens, float* __restrict__ out) {
    int b = blockIdx.y;
    int len = lens[b];
    int s0 = blockIdx.x * 128;
    if (s0 >= len) return;
    int send = s0 + 128; if (send > len) send = len;
    int t  = threadIdx.x;
    int e4 = t & 127;   // float4 column
    int sr = t >> 7;    // row group 0..3
    const float* ap = attn + (size_t)b * S_;
    f32x4 acc = {0.f, 0.f, 0.f, 0.f};
    const float* base = A + (size_t)b * S_ * E_;
    for (int s = s0 + sr; s < send; s += 4) {
        float wgt = ap[s];
        f32x4 v = *(const f32x4*)(base + (size_t)s * E_ + e4 * 4);
        acc += wgt * v;
    }
    __shared__ f32x4 red[4][128];
    red[sr][e4] = acc;
    __syncthreads();
    if (t < 128) {
        f32x4 tot = red[0][t] + red[1][t] + red[2][t] + red[3][t];
        float* o = out + (size_t)b * E_ + t * 4;
        atomicAdd(o + 0, tot[0]);
        atomicAdd(o + 1, tot[1]);
        atomicAdd(o + 2, tot[2]);
        atomicAdd(o + 3, tot[3]);
    }
}

extern "C" void kernel_launch(void* const* d_in, const int* in_sizes, int n_in,
                              void* d_out, int out_size, void* d_ws, size_t ws_size,
                              hipStream_t stream) {
    const float* embeds = (const float*)d_in[0];
    const int*   lens   = (const int*)d_in[1];
    const float* ctx    = (const float*)d_in[2];
    const float* Ww     = (const float*)d_in[3];
    const float* bw     = (const float*)d_in[4];
    const float* Wc     = (const float*)d_in[5];
    const float* bc     = (const float*)d_in[6];
    const float* wh     = (const float*)d_in[7];
    float* out  = (float*)d_out;
    float* feat = out;                 // [B, E]
    float* attn = out + B_ * E_;       // [B, S] (raw scores, then attn; 0 for s>=len)

    unsigned short* Wb = (unsigned short*)d_ws;                                  // 256 KB
    float* cb = (float*)((char*)d_ws + (size_t)H_ * E_ * sizeof(unsigned short)); // 64 KB

    hipMemsetAsync(feat, 0, (size_t)B_ * E_ * sizeof(float), stream);
    prep_w<<<(H_ * E_) / 1024, 256, 0, stream>>>(Ww, Wb);
    prep_ctx<<<B_, 256, 0, stream>>>(ctx, Wc, bc, bw, cb);
    scores_kernel<<<dim3(B_ * S_ / BM), 512, 0, stream>>>(embeds, Wb, cb, wh, lens, attn);
    softmax_kernel<<<B_, 256, 0, stream>>>(lens, attn);
    wsum_kernel<<<dim3(S_ / 128, B_), 512, 0, stream>>>(embeds, attn, lens, feat);
}